// Round 12
// baseline (63.705 us; speedup 1.0000x reference)
//
#include <hip/hip_runtime.h>

#define B_   4
#define LQ_  256
#define LK_  512
#define DIN_ 512
#define H_   256
#define DV_  512

#define L2E 1.4426950408889634f   // log2(e)
// tanh(x) = 1 - 2/(e^{2x}+1);  e^{2(q+k)} = (e^q * e^k)^2.
// combine stores eq = 2^clamp(qp*L2E,±126) (finite, nonzero -> no NaN;
// p*p overflow -> inf -> rcp=0 -> exact tanh saturation).

// =====================================================================
// Kernel A: proj partial, thread-per-h. Tile = 16 rows x 256 h x 128 d.
// W loads are CONTIGUOUS 1KB/instruction (d-major, lane=h) - no L2 stride.
// X tile staged in LDS (8.5 KB), consumed as uniform-address b128
// broadcasts (conflict-free). 16 independent acc chains/thread.
// grid = Q: 64rt x 4ds = 256  +  K: 128rt x 4ds = 512  -> 768 blocks,
// all LDS-resident (~3/CU), dead K tiles exit.
// out: qpart[ds][(b,i)][h], ekpart[ds][(b,j)][h]  (row-major, coalesced)
// =====================================================================
__global__ __launch_bounds__(256) void proj_partial_kernel(
    const float* __restrict__ Q, const float* __restrict__ K,
    const float* __restrict__ Wq, const float* __restrict__ Wk,
    const int* __restrict__ valid_lens,
    float* __restrict__ qpart, float* __restrict__ ekpart) {
  __shared__ float xs[16][132];
  const int blk = blockIdx.x;
  const bool isQ = blk < 256;
  int flat, ds;
  if (isQ) {
    const int u = blk;
    ds = u & 3;
    flat = (u >> 2) * 16;                 // global Q row 0..1023
  } else {
    const int u = blk - 256;
    ds = u & 3;
    const int rt = u >> 2;                // 0..127, batch-interleaved
    const int b = rt & 3;
    const int rl = (rt >> 2) * 16;        // 0..496
    if (rl >= valid_lens[b]) return;      // dead K tile (uniform exit)
    flat = b * LK_ + rl;                  // global K row 0..2047
  }
  const float* __restrict__ X = (isQ ? Q : K) + (size_t)flat * DIN_ + ds * 128;
  const float* __restrict__ W = (isQ ? Wq : Wk) + (size_t)(ds * 128) * H_;
  const int t = threadIdx.x;              // = h column

  // stage X tile 16 rows x 128 d: 512 f4 / 256 thr = 2 each (512B rows)
#pragma unroll
  for (int u = 0; u < 2; ++u) {
    const int f = t + 256 * u;            // 0..511
    const int r = f >> 5, c4 = (f & 31) << 2;
    *(float4*)&xs[r][c4] = *(const float4*)&X[(size_t)r * DIN_ + c4];
  }
  __syncthreads();

  float acc[16];
#pragma unroll
  for (int r = 0; r < 16; ++r) acc[r] = 0.f;

  for (int d = 0; d < 128; d += 8) {
    float w[8];
#pragma unroll
    for (int u = 0; u < 8; ++u)
      w[u] = W[(size_t)(d + u) * H_ + t];          // contiguous 1KB/wave, 8 in flight
#pragma unroll
    for (int r = 0; r < 16; ++r) {
      const float4 xa = *(const float4*)&xs[r][d];      // uniform addr: broadcast
      const float4 xb = *(const float4*)&xs[r][d + 4];
      acc[r] = fmaf(xa.x, w[0], acc[r]); acc[r] = fmaf(xa.y, w[1], acc[r]);
      acc[r] = fmaf(xa.z, w[2], acc[r]); acc[r] = fmaf(xa.w, w[3], acc[r]);
      acc[r] = fmaf(xb.x, w[4], acc[r]); acc[r] = fmaf(xb.y, w[5], acc[r]);
      acc[r] = fmaf(xb.z, w[6], acc[r]); acc[r] = fmaf(xb.w, w[7], acc[r]);
    }
  }

  float* __restrict__ dst = isQ ? (qpart + (size_t)ds * (B_ * LQ_ * H_))
                                : (ekpart + (size_t)ds * (B_ * LK_ * H_));
#pragma unroll
  for (int r = 0; r < 16; ++r)
    dst[(size_t)(flat + r) * H_ + t] = acc[r];     // coalesced 1KB stores
}

// =====================================================================
// Kernel B: combine 4 d-partials + exp convert (pure elementwise float4).
// eq[(b,i)][h], ek[(b,j)][h] row-major. Block 0 computes wsum.
// =====================================================================
__global__ __launch_bounds__(512) void combine_exp_kernel(
    const float* __restrict__ qpart, const float* __restrict__ ekpart,
    const float* __restrict__ wv,
    float* __restrict__ eq, float* __restrict__ ek, float* __restrict__ wsum) {
  const int idx = blockIdx.x * 512 + threadIdx.x;
  const int NQ4 = B_ * LQ_ * H_ / 4;     // 65536
  const float4* src;
  float4* dst;
  size_t stride4;
  int k4;
  if (idx < NQ4) {
    src = (const float4*)qpart; dst = (float4*)eq;
    stride4 = NQ4; k4 = idx;
  } else {
    src = (const float4*)ekpart; dst = (float4*)ek;
    stride4 = B_ * LK_ * H_ / 4; k4 = idx - NQ4;
  }
  float4 a = src[k4];
  float4 b1 = src[stride4 + k4];
  float4 c = src[2 * stride4 + k4];
  float4 d = src[3 * stride4 + k4];
  float4 o;
  o.x = exp2f(fminf(fmaxf((a.x + b1.x + c.x + d.x) * L2E, -126.f), 126.f));
  o.y = exp2f(fminf(fmaxf((a.y + b1.y + c.y + d.y) * L2E, -126.f), 126.f));
  o.z = exp2f(fminf(fmaxf((a.z + b1.z + c.z + d.z) * L2E, -126.f), 126.f));
  o.w = exp2f(fminf(fmaxf((a.w + b1.w + c.w + d.w) * L2E, -126.f), 126.f));
  dst[k4] = o;

  if (blockIdx.x == 0 && threadIdx.x < 64) {
    const int t = threadIdx.x;
    float s = wv[t] + wv[t + 64] + wv[t + 128] + wv[t + 192];
#pragma unroll
    for (int off = 32; off; off >>= 1) s += __shfl_xor(s, off);
    if (t == 0) *wsum = s;
  }
}

// =====================================================================
// Kernel C: LDS-tiled scores. Block = (b, 32 i, 32 j), thread 2i x 2j.
//   sc[(b,i)][j] = Wsum - 2*sum_h wv[h]*rcp((eq*ek)^2+1)
// ek_s width 33: staging writes 8-way (was 32-way at 36); compute reads
// as b32 pairs -> 16 banks x 4-lane broadcast, conflict-free.
// grid = B*(LQ/32)*(LK/32) = 512; dead j-tiles exit.
// =====================================================================
__global__ __launch_bounds__(256) void scores_kernel(
    const float* __restrict__ eq, const float* __restrict__ ek,
    const float* __restrict__ wv, const float* __restrict__ wsum,
    const int* __restrict__ valid_lens, float* __restrict__ sc) {
  __shared__ float eq_s[32][260];   // 33.3 KB
  __shared__ float ek_s[256][33];   // 33.8 KB
  __shared__ float wv_s[260];

  const int blk = blockIdx.x;
  const int b  = blk & 3;
  const int it = (blk >> 2) & 7;
  const int jt = blk >> 5;
  const int vl = valid_lens[b];
  if (jt * 32 >= vl) return;
  const int t = threadIdx.x;
  const int tx = t & 15, ty = t >> 4;
  const int i0 = it * 32, j0 = jt * 32;

  // stage eq rows i0..i0+31 (each wave: one contiguous 1KB row)
  const float* __restrict__ eqb = eq + ((size_t)(b * LQ_ + i0)) * H_;
#pragma unroll
  for (int u = 0; u < 8; ++u) {
    const int f = t + 256 * u;
    const int r = f >> 6, c4 = (f & 63) << 2;
    *(float4*)&eq_s[r][c4] = *(const float4*)&eqb[(size_t)r * H_ + c4];
  }
  // stage ek rows j0..j0+31 transposed into ek_s[h][j]
  const float* __restrict__ ekb = ek + ((size_t)(b * LK_ + j0)) * H_;
  {
    const int hq = t & 63, jg = t >> 6;
#pragma unroll
    for (int p = 0; p < 8; ++p) {
      const int jj = jg + 4 * p;
      const float4 v = *(const float4*)&ekb[(size_t)jj * H_ + 4 * hq];
      ek_s[4 * hq][jj]     = v.x;
      ek_s[4 * hq + 1][jj] = v.y;
      ek_s[4 * hq + 2][jj] = v.z;
      ek_s[4 * hq + 3][jj] = v.w;
    }
  }
  if (t < 64) {
#pragma unroll
    for (int u = 0; u < 4; ++u) wv_s[t + 64 * u] = wv[t + 64 * u];
  }
  __syncthreads();

  const float Wsum = *wsum;
  float a00 = 0.f, a01 = 0.f, a10 = 0.f, a11 = 0.f;
#pragma unroll 2
  for (int hq = 0; hq < 64; ++hq) {
    const float4 q0 = *(const float4*)&eq_s[2 * ty][4 * hq];
    const float4 q1 = *(const float4*)&eq_s[2 * ty + 1][4 * hq];
    const float4 w4 = *(const float4*)&wv_s[4 * hq];
    const float qa[4] = {q0.x, q0.y, q0.z, q0.w};
    const float qb[4] = {q1.x, q1.y, q1.z, q1.w};
    const float ww[4] = {w4.x, w4.y, w4.z, w4.w};
#pragma unroll
    for (int u = 0; u < 4; ++u) {
      const float kx = ek_s[4 * hq + u][2 * tx];
      const float ky = ek_s[4 * hq + u][2 * tx + 1];
      float p;
      p = qa[u] * kx; a00 = fmaf(ww[u], __builtin_amdgcn_rcpf(fmaf(p, p, 1.f)), a00);
      p = qa[u] * ky; a01 = fmaf(ww[u], __builtin_amdgcn_rcpf(fmaf(p, p, 1.f)), a01);
      p = qb[u] * kx; a10 = fmaf(ww[u], __builtin_amdgcn_rcpf(fmaf(p, p, 1.f)), a10);
      p = qb[u] * ky; a11 = fmaf(ww[u], __builtin_amdgcn_rcpf(fmaf(p, p, 1.f)), a11);
    }
  }
  const int i = i0 + 2 * ty, j = j0 + 2 * tx;
  float2 r0 = {fmaf(-2.f, a00, Wsum), fmaf(-2.f, a01, Wsum)};
  float2 r1 = {fmaf(-2.f, a10, Wsum), fmaf(-2.f, a11, Wsum)};
  *(float2*)&sc[(size_t)(b * LQ_ + i) * LK_ + j] = r0;
  *(float2*)&sc[(size_t)(b * LQ_ + i + 1) * LK_ + j] = r1;
}

// =====================================================================
// Kernel D: masked softmax + AV, TI=4 rows/block, 512 thr, AV unroll x8.
// =====================================================================
__global__ __launch_bounds__(512) void softmax_av_kernel(
    const float* __restrict__ sc, const float* __restrict__ V,
    const int* __restrict__ valid_lens, float* __restrict__ out) {
  __shared__ float4 p4s[LK_];
  __shared__ float redm[8][4];
  __shared__ float reds[8][4];

  const int blk = blockIdx.x;
  const int b = blk >> 6;
  const int i0 = (blk & 63) * 4;
  const int vl = valid_lens[b];
  const int t = threadIdx.x;        // j
  const int lane = t & 63, wave = t >> 6;

  const float* __restrict__ srow = sc + (size_t)(b * LQ_ + i0) * LK_;
  const bool valid = t < vl;
  float s[4], m[4];
#pragma unroll
  for (int ii = 0; ii < 4; ++ii) {
    s[ii] = valid ? srow[ii * LK_ + t] : -3.0e38f;
    m[ii] = s[ii];
  }
#pragma unroll
  for (int off = 32; off; off >>= 1)
#pragma unroll
    for (int ii = 0; ii < 4; ++ii) m[ii] = fmaxf(m[ii], __shfl_xor(m[ii], off));
  if (lane == 0)
#pragma unroll
    for (int ii = 0; ii < 4; ++ii) redm[wave][ii] = m[ii];
  __syncthreads();
  float e[4], sum[4];
#pragma unroll
  for (int ii = 0; ii < 4; ++ii) {
    float mx = redm[0][ii];
#pragma unroll
    for (int w = 1; w < 8; ++w) mx = fmaxf(mx, redm[w][ii]);
    e[ii] = valid ? __expf(s[ii] - mx) : 0.f;
    sum[ii] = e[ii];
  }
#pragma unroll
  for (int off = 32; off; off >>= 1)
#pragma unroll
    for (int ii = 0; ii < 4; ++ii) sum[ii] += __shfl_xor(sum[ii], off);
  if (lane == 0)
#pragma unroll
    for (int ii = 0; ii < 4; ++ii) reds[wave][ii] = sum[ii];
  __syncthreads();
  {
    float4 pv;
    float tot[4];
#pragma unroll
    for (int ii = 0; ii < 4; ++ii) {
      tot[ii] = reds[0][ii];
#pragma unroll
      for (int w = 1; w < 8; ++w) tot[ii] += reds[w][ii];
    }
    pv.x = e[0] * __builtin_amdgcn_rcpf(tot[0]);
    pv.y = e[1] * __builtin_amdgcn_rcpf(tot[1]);
    pv.z = e[2] * __builtin_amdgcn_rcpf(tot[2]);
    pv.w = e[3] * __builtin_amdgcn_rcpf(tot[3]);
    p4s[t] = pv;
  }
  __syncthreads();

  const float* __restrict__ Vb = V + (size_t)b * LK_ * DV_ + t;
  float a[4] = {0.f, 0.f, 0.f, 0.f};
  int j = 0;
  const int jv = vl & ~7;
  for (; j < jv; j += 8) {
    float v[8];
#pragma unroll
    for (int u = 0; u < 8; ++u) v[u] = Vb[(size_t)(j + u) * DV_];
#pragma unroll
    for (int u = 0; u < 8; ++u) {
      const float4 pp = p4s[j + u];
      a[0] = fmaf(pp.x, v[u], a[0]); a[1] = fmaf(pp.y, v[u], a[1]);
      a[2] = fmaf(pp.z, v[u], a[2]); a[3] = fmaf(pp.w, v[u], a[3]);
    }
  }
  for (; j < vl; ++j) {
    const float v = Vb[(size_t)j * DV_];
    const float4 pp = p4s[j];
    a[0] = fmaf(pp.x, v, a[0]); a[1] = fmaf(pp.y, v, a[1]);
    a[2] = fmaf(pp.z, v, a[2]); a[3] = fmaf(pp.w, v, a[3]);
  }
#pragma unroll
  for (int ii = 0; ii < 4; ++ii)
    out[(size_t)(b * LQ_ + i0 + ii) * DV_ + t] = a[ii];
}

extern "C" void kernel_launch(void* const* d_in, const int* in_sizes, int n_in,
                              void* d_out, int out_size, void* d_ws, size_t ws_size,
                              hipStream_t stream) {
  const float* queries    = (const float*)d_in[0];
  const float* keys       = (const float*)d_in[1];
  const float* values     = (const float*)d_in[2];
  const int*   valid_lens = (const int*)d_in[3];
  const float* Wq         = (const float*)d_in[4];
  const float* Wk         = (const float*)d_in[5];
  const float* wv         = (const float*)d_in[6];
  float* out = (float*)d_out;

  char* ws = (char*)d_ws;
  float* qpart  = (float*)ws;                           // 4 x 1 MB  @ 0
  float* ekpart = (float*)(ws + (size_t)( 4 << 20));    // 4 x 2 MB  @ 4 MB
  float* eq     = (float*)(ws + (size_t)(12 << 20));    // 1 MB      @ 12 MB
  float* ek     = (float*)(ws + (size_t)(13 << 20));    // 2 MB      @ 13 MB
  float* sc     = (float*)(ws + (size_t)(15 << 20));    // 2 MB      @ 15 MB
  float* wsum   = (float*)(ws + (size_t)(17 << 20));    // 4 B       @ 17 MB

  proj_partial_kernel<<<768, 256, 0, stream>>>(
      queries, keys, Wq, Wk, valid_lens, qpart, ekpart);
  combine_exp_kernel<<<384, 512, 0, stream>>>(
      qpart, ekpart, wv, eq, ek, wsum);
  scores_kernel<<<512, 256, 0, stream>>>(
      eq, ek, wv, wsum, valid_lens, sc);
  softmax_av_kernel<<<B_ * (LQ_ / 4), 512, 0, stream>>>(
      sc, values, valid_lens, out);
}